// Round 1
// baseline (3545.244 us; speedup 1.0000x reference)
//
#include <hip/hip_runtime.h>
#include <hip/hip_bf16.h>
#include <cstddef>

#define N_NODES 30000
#define N_EDGES 100000
#define N_TYPES 6
#define D_IN 128
#define HC 256
#define NH 8
#define CH 32

// ---------------- generic fill ----------------
__global__ void fillk(float* __restrict__ p, float v, int n) {
    int g = blockIdx.x * blockDim.x + threadIdx.x;
    if (g < n) p[g] = v;
}

// ---------------- fp32 tiled GEMM: C[M,N] = A[M,K] @ B[K,N] ----------------
// block 256 threads, 64x64 tile, 4x4 per thread, K-tile 16. N % 64 == 0, K % 16 == 0.
__global__ __launch_bounds__(256) void gemm_tile(const float* __restrict__ A,
                                                 const float* __restrict__ B,
                                                 float* __restrict__ C,
                                                 int M, int K, int N) {
    __shared__ float As[16 * 68];   // stride 68: aligned float4 reads + 2-way-max bank writes
    __shared__ float Bs[16 * 64];
    int tid = threadIdx.x;
    int tx = tid & 15, ty = tid >> 4;
    int m0 = blockIdx.x * 64;
    int n0 = blockIdx.y * 64;
    float acc[4][4] = {};
    for (int k0 = 0; k0 < K; k0 += 16) {
        #pragma unroll
        for (int i = 0; i < 4; ++i) {
            int lin = i * 256 + tid;
            int k = lin & 15, m = lin >> 4;
            int gm = m0 + m;
            As[k * 68 + m] = (gm < M) ? A[(size_t)gm * K + k0 + k] : 0.f;
        }
        #pragma unroll
        for (int i = 0; i < 4; ++i) {
            int lin = i * 256 + tid;
            int k = lin >> 6, n = lin & 63;
            Bs[k * 64 + n] = B[(size_t)(k0 + k) * N + n0 + n];
        }
        __syncthreads();
        #pragma unroll
        for (int kk = 0; kk < 16; ++kk) {
            float4 av = *(const float4*)&As[kk * 68 + ty * 4];
            float4 bv = *(const float4*)&Bs[kk * 64 + tx * 4];
            float a[4] = {av.x, av.y, av.z, av.w};
            float b[4] = {bv.x, bv.y, bv.z, bv.w};
            #pragma unroll
            for (int i = 0; i < 4; ++i)
                #pragma unroll
                for (int j = 0; j < 4; ++j)
                    acc[i][j] += a[i] * b[j];
        }
        __syncthreads();
    }
    #pragma unroll
    for (int i = 0; i < 4; ++i) {
        int gm = m0 + ty * 4 + i;
        if (gm < M) {
            float4 v = make_float4(acc[i][0], acc[i][1], acc[i][2], acc[i][3]);
            *(float4*)&C[(size_t)gm * N + n0 + tx * 4] = v;
        }
    }
}

// ---------------- e[n,h] = sum_c H[n,h*32+c] * att[h*32+c] ----------------
__global__ void att_reduce(const float* __restrict__ Hm, const float* __restrict__ att,
                           float* __restrict__ out, int NN) {
    int g = blockIdx.x * blockDim.x + threadIdx.x;
    if (g >= NN) return;
    int n = g >> 3, h = g & 7;
    const float* row = Hm + (size_t)n * HC + h * CH;
    const float* a = att + h * CH;
    float acc = 0.f;
    #pragma unroll
    for (int c = 0; c < CH; ++c) acc += row[c] * a[c];
    out[g] = acc;
}

// ---------------- per-edge exp(leaky(es+ed)) and segment denominator ----------------
__global__ void edge_exp_sum(const float* __restrict__ es, const float* __restrict__ ed,
                             const int* __restrict__ src, const int* __restrict__ dst,
                             float* __restrict__ exb, float* __restrict__ segsum) {
    int g = blockIdx.x * blockDim.x + threadIdx.x;
    if (g >= N_EDGES * NH) return;
    int e = g >> 3, h = g & 7;
    int s = src[e], d = dst[e];
    float x = es[s * NH + h] + ed[d * NH + h];
    x = (x >= 0.f) ? x : 0.2f * x;
    float ex = expf(x);
    exb[g] = ex;
    atomicAdd(&segsum[d * NH + h], ex);
}

// ---------------- message scatter: out[dst] += hs[src] * alpha ----------------
__global__ __launch_bounds__(256) void msg_scatter(const float* __restrict__ exb,
                                                   const float* __restrict__ segsum,
                                                   const int* __restrict__ src,
                                                   const int* __restrict__ dst,
                                                   const float* __restrict__ hs,
                                                   float* __restrict__ out,
                                                   float* __restrict__ alpha_out) {
    int e = blockIdx.x;
    int tid = threadIdx.x;
    int s = src[e], d = dst[e];
    int h = tid >> 5;
    float alpha = exb[e * NH + h] / (segsum[d * NH + h] + 1e-16f);
    float v = hs[(size_t)s * HC + tid] * alpha;
    atomicAdd(&out[(size_t)d * HC + tid], v);
    if (alpha_out != nullptr && tid < NH) {
        alpha_out[e * NH + tid] = exb[e * NH + tid] / (segsum[d * NH + tid] + 1e-16f);
    }
}

// ---------------- layernorm (+bias in) + relu, in place, row = 256 ----------------
__global__ __launch_bounds__(256) void ln_relu(float* __restrict__ x, const float* __restrict__ bias,
                                               const float* __restrict__ g, const float* __restrict__ b) {
    int n = blockIdx.x;
    int tid = threadIdx.x;
    float v = x[(size_t)n * HC + tid] + bias[tid];
    float s1 = v, s2 = v * v;
    #pragma unroll
    for (int off = 32; off; off >>= 1) {
        s1 += __shfl_down(s1, off);
        s2 += __shfl_down(s2, off);
    }
    __shared__ float w1[4], w2[4];
    __shared__ float mu_s, rstd_s;
    int wid = tid >> 6, lane = tid & 63;
    if (lane == 0) { w1[wid] = s1; w2[wid] = s2; }
    __syncthreads();
    if (tid == 0) {
        float t1 = w1[0] + w1[1] + w1[2] + w1[3];
        float t2 = w2[0] + w2[1] + w2[2] + w2[3];
        float mu = t1 * (1.f / 256.f);
        float var = t2 * (1.f / 256.f) - mu * mu;
        mu_s = mu;
        rstd_s = rsqrtf(var + 1e-5f);
    }
    __syncthreads();
    float y = (v - mu_s) * rstd_s * g[tid] + b[tid];
    x[(size_t)n * HC + tid] = (y > 0.f) ? y : 0.f;
}

// ---------------- column-sum accumulate (for mean pooling), 256 cols ----------------
__global__ __launch_bounds__(256) void pool_accum(const float* __restrict__ x, float* __restrict__ sums) {
    int tid = threadIdx.x;
    int r0 = blockIdx.x * 300;
    int r1 = r0 + 300;
    if (r1 > N_NODES) r1 = N_NODES;
    float acc = 0.f;
    for (int r = r0; r < r1; ++r) acc += x[(size_t)r * HC + tid];
    atomicAdd(&sums[tid], acc);
}

// ---------------- x_pkg column-sum (128 cols) ----------------
__global__ __launch_bounds__(128) void pkg_accum(const float* __restrict__ x, float* __restrict__ sums) {
    int tid = threadIdx.x;
    int r0 = blockIdx.x * 300;
    int r1 = r0 + 300;
    if (r1 > N_NODES) r1 = N_NODES;
    float acc = 0.f;
    for (int r = r0; r < r1; ++r) acc += x[(size_t)r * D_IN + tid];
    atomicAdd(&sums[tid], acc);
}

// ---------------- final classifier dot ----------------
__global__ __launch_bounds__(256) void logits_k(const float* __restrict__ psums,
                                                const float* __restrict__ ksums,
                                                const float* __restrict__ Wc,
                                                const float* __restrict__ bc,
                                                float* __restrict__ out) {
    int tid = threadIdx.x;
    const float inv = 1.f / (float)N_NODES;
    float acc = 0.f;
    for (int i = tid; i < N_TYPES * HC; i += 256) acc += psums[i] * inv * Wc[i];
    if (tid < D_IN) acc += ksums[tid] * inv * Wc[N_TYPES * HC + tid];
    #pragma unroll
    for (int off = 32; off; off >>= 1) acc += __shfl_down(acc, off);
    __shared__ float w[4];
    if ((tid & 63) == 0) w[tid >> 6] = acc;
    __syncthreads();
    if (tid == 0) out[0] = w[0] + w[1] + w[2] + w[3] + bc[0];
}

static inline void zero_f(float* p, int n, hipStream_t stream) {
    fillk<<<(n + 255) / 256, 256, 0, stream>>>(p, 0.f, n);
}

extern "C" void kernel_launch(void* const* d_in, const int* in_sizes, int n_in,
                              void* d_out, int out_size, void* d_ws, size_t ws_size,
                              hipStream_t stream) {
    const float* x_pkg    = (const float*)d_in[0];
    const float* x_tgt    = (const float*)d_in[1];
    const int*   ei       = (const int*)d_in[2];
    const float* W1_src   = (const float*)d_in[3];
    const float* W1_dst   = (const float*)d_in[4];
    const float* att1_src = (const float*)d_in[5];
    const float* att1_dst = (const float*)d_in[6];
    const float* b1       = (const float*)d_in[7];
    const float* W2_src   = (const float*)d_in[8];
    const float* W2_dst   = (const float*)d_in[9];
    const float* att2_src = (const float*)d_in[10];
    const float* att2_dst = (const float*)d_in[11];
    const float* b2       = (const float*)d_in[12];
    const float* gamma    = (const float*)d_in[13];
    const float* beta     = (const float*)d_in[14];
    const float* Wc       = (const float*)d_in[15];
    const float* bc       = (const float*)d_in[16];
    float* out = (float*)d_out;

    float* ws = (float*)d_ws;
    const size_t BIG = (size_t)N_NODES * HC;          // 7,680,000
    float* bufA   = ws;
    float* bufB   = bufA + BIG;
    float* es     = bufB + BIG;                        // 240,000
    float* ed     = es + (size_t)N_NODES * NH;
    float* segsum = ed + (size_t)N_NODES * NH;
    float* exb    = segsum + (size_t)N_NODES * NH;     // 800,000
    float* psums  = exb + (size_t)N_EDGES * NH;        // 1536
    float* ksums  = psums + N_TYPES * HC;              // 128

    dim3 gemm_grid((N_NODES + 63) / 64, HC / 64);
    const int NN8 = N_NODES * NH;
    const int E8 = N_EDGES * NH;

    zero_f(psums, N_TYPES * HC, stream);
    zero_f(ksums, D_IN, stream);
    pkg_accum<<<100, 128, 0, stream>>>(x_pkg, ksums);

    for (int t = 0; t < N_TYPES; ++t) {
        const int* src_t = ei + (size_t)t * 2 * N_EDGES;
        const int* dst_t = src_t + N_EDGES;

        // ---- layer 1 ----
        // hd1 = x_tgt[t] @ W1_dst[t]  -> bufB ; ed1
        gemm_tile<<<gemm_grid, 256, 0, stream>>>(x_tgt + (size_t)t * N_NODES * D_IN,
                                                 W1_dst + (size_t)t * D_IN * HC, bufB,
                                                 N_NODES, D_IN, HC);
        att_reduce<<<(NN8 + 255) / 256, 256, 0, stream>>>(bufB, att1_dst + t * HC, ed, NN8);
        // hs1 = x_pkg @ W1_src[t] -> bufA ; es1
        gemm_tile<<<gemm_grid, 256, 0, stream>>>(x_pkg, W1_src + (size_t)t * D_IN * HC, bufA,
                                                 N_NODES, D_IN, HC);
        att_reduce<<<(NN8 + 255) / 256, 256, 0, stream>>>(bufA, att1_src + t * HC, es, NN8);
        // softmax denominators
        zero_f(segsum, NN8, stream);
        edge_exp_sum<<<(E8 + 255) / 256, 256, 0, stream>>>(es, ed, src_t, dst_t, exb, segsum);
        // out1 accumulation -> bufB (hd1 dead)
        zero_f(bufB, (int)BIG, stream);
        msg_scatter<<<N_EDGES, 256, 0, stream>>>(exb, segsum, src_t, dst_t, bufA, bufB, nullptr);
        ln_relu<<<N_NODES, 256, 0, stream>>>(bufB, b1 + t * HC, gamma + t * HC, beta + t * HC);

        // ---- layer 2 ----
        // hd2 = x1 @ W2_dst[t] -> bufA (hs1 dead) ; ed2
        gemm_tile<<<gemm_grid, 256, 0, stream>>>(bufB, W2_dst + (size_t)t * HC * HC, bufA,
                                                 N_NODES, HC, HC);
        att_reduce<<<(NN8 + 255) / 256, 256, 0, stream>>>(bufA, att2_dst + t * HC, ed, NN8);
        // hs2 = x_pkg @ W2_src[t] -> bufB (x1 dead) ; es2
        gemm_tile<<<gemm_grid, 256, 0, stream>>>(x_pkg, W2_src + (size_t)t * D_IN * HC, bufB,
                                                 N_NODES, D_IN, HC);
        att_reduce<<<(NN8 + 255) / 256, 256, 0, stream>>>(bufB, att2_src + t * HC, es, NN8);
        zero_f(segsum, NN8, stream);
        edge_exp_sum<<<(E8 + 255) / 256, 256, 0, stream>>>(es, ed, src_t, dst_t, exb, segsum);
        // out2 accumulation -> bufA (hd2 dead); alpha2 -> d_out
        zero_f(bufA, (int)BIG, stream);
        msg_scatter<<<N_EDGES, 256, 0, stream>>>(exb, segsum, src_t, dst_t, bufB, bufA,
                                                 out + 1 + (size_t)t * N_EDGES * NH);
        ln_relu<<<N_NODES, 256, 0, stream>>>(bufA, b2 + t * HC, gamma + t * HC, beta + t * HC);
        pool_accum<<<100, 256, 0, stream>>>(bufA, psums + t * HC);
    }

    logits_k<<<1, 256, 0, stream>>>(psums, ksums, Wc, bc, out);
}

// Round 2
// 2261.123 us; speedup vs baseline: 1.5679x; 1.5679x over previous
//
#include <hip/hip_runtime.h>
#include <hip/hip_bf16.h>
#include <cstddef>

#define N_NODES 30000
#define N_EDGES 100000
#define N_TYPES 6
#define D_IN 128
#define HC 256
#define NH 8
#define CH 32

typedef __attribute__((ext_vector_type(8))) unsigned short ushort8_t;
typedef __attribute__((ext_vector_type(8))) __bf16 bf16x8;
typedef __attribute__((ext_vector_type(4))) float floatx4;

__device__ inline unsigned short f2bf(float f) {
    unsigned u = __float_as_uint(f);
    u += 0x7fffu + ((u >> 16) & 1u);
    return (unsigned short)(u >> 16);
}

// ---------------- zero fill (float4) ----------------
__global__ void zero4(float4* __restrict__ p, int n4) {
    int g = blockIdx.x * blockDim.x + threadIdx.x;
    if (g < n4) p[g] = make_float4(0.f, 0.f, 0.f, 0.f);
}

// ---------------- MFMA bf16 GEMM with fused attention-logit epilogue ----------------
// C[M,N] = A[M,K] @ B[K,N] (fp32 in, bf16 compute, fp32 out).
// Optionally writes C (Cp != nullptr). Always writes e_out[n,h] = sum_c C[n,h*32+c]*att[h*32+c].
// Block: 256 thr (4 waves), tile 64(M) x 64(N), BK=32. N must be 256, K % 32 == 0.
__global__ __launch_bounds__(256) void gemm_att(const float* __restrict__ A,
                                                const float* __restrict__ B,
                                                float* __restrict__ Cp,
                                                const float* __restrict__ att,
                                                float* __restrict__ e_out,
                                                int M, int K, int N) {
    __shared__ unsigned short As[64 * 40];   // As[m][k], stride 40
    __shared__ unsigned short Bs[64 * 40];   // Bs[n][k] (transposed), stride 40

    const int tid = threadIdx.x;
    const int w = tid >> 6;          // wave 0..3
    const int lane = tid & 63;
    const int col = lane & 15;
    const int quad = lane >> 4;
    const int m0 = blockIdx.x * 64;
    const int n0 = blockIdx.y * 64;

    // staging maps
    const int am = tid >> 2;             // 0..63
    const int ak = (tid & 3) * 8;        // 0,8,16,24
    const int bk2 = (tid >> 4) * 2;      // 0..30
    const int bn4 = (tid & 15) * 4;      // 0..60

    floatx4 acc[4];
    #pragma unroll
    for (int ct = 0; ct < 4; ++ct) acc[ct] = (floatx4){0.f, 0.f, 0.f, 0.f};

    for (int k0 = 0; k0 < K; k0 += 32) {
        // ---- stage A (64 x 32) ----
        {
            int gm = m0 + am;
            float4 f0 = make_float4(0, 0, 0, 0), f1 = make_float4(0, 0, 0, 0);
            if (gm < M) {
                const float* ap = A + (size_t)gm * K + k0 + ak;
                f0 = *(const float4*)ap;
                f1 = *(const float4*)(ap + 4);
            }
            ushort8_t v;
            v[0] = f2bf(f0.x); v[1] = f2bf(f0.y); v[2] = f2bf(f0.z); v[3] = f2bf(f0.w);
            v[4] = f2bf(f1.x); v[5] = f2bf(f1.y); v[6] = f2bf(f1.z); v[7] = f2bf(f1.w);
            *(ushort8_t*)&As[am * 40 + ak] = v;
        }
        // ---- stage B transposed (32 x 64 -> Bs[n][k]) ----
        {
            const float4 r0 = *(const float4*)&B[(size_t)(k0 + bk2) * N + n0 + bn4];
            const float4 r1 = *(const float4*)&B[(size_t)(k0 + bk2 + 1) * N + n0 + bn4];
            float a0[4] = {r0.x, r0.y, r0.z, r0.w};
            float a1[4] = {r1.x, r1.y, r1.z, r1.w};
            #pragma unroll
            for (int j = 0; j < 4; ++j) {
                unsigned pk = (unsigned)f2bf(a0[j]) | ((unsigned)f2bf(a1[j]) << 16);
                *(unsigned*)&Bs[(bn4 + j) * 40 + bk2] = pk;
            }
        }
        __syncthreads();
        // ---- compute: wave w -> rows w*16..w*16+15, all 64 cols ----
        {
            ushort8_t araw = *(const ushort8_t*)&As[(w * 16 + col) * 40 + quad * 8];
            bf16x8 af = __builtin_bit_cast(bf16x8, araw);
            #pragma unroll
            for (int ct = 0; ct < 4; ++ct) {
                ushort8_t braw = *(const ushort8_t*)&Bs[(ct * 16 + col) * 40 + quad * 8];
                bf16x8 bf = __builtin_bit_cast(bf16x8, braw);
                acc[ct] = __builtin_amdgcn_mfma_f32_16x16x32_bf16(af, bf, acc[ct], 0, 0, 0);
            }
        }
        __syncthreads();
    }

    // ---- epilogue: optional C write ----
    if (Cp != nullptr) {
        #pragma unroll
        for (int ct = 0; ct < 4; ++ct) {
            #pragma unroll
            for (int r = 0; r < 4; ++r) {
                int gm = m0 + w * 16 + quad * 4 + r;
                if (gm < M) Cp[(size_t)gm * N + n0 + ct * 16 + col] = acc[ct][r];
            }
        }
    }

    // ---- fused attention logits: e[n,h] for heads n0/32, n0/32+1 ----
    float attv[4];
    #pragma unroll
    for (int ct = 0; ct < 4; ++ct) attv[ct] = att[n0 + ct * 16 + col];
    const int hbase = n0 >> 5;
    #pragma unroll
    for (int r = 0; r < 4; ++r) {
        float h0v = acc[0][r] * attv[0] + acc[1][r] * attv[1];
        float h1v = acc[2][r] * attv[2] + acc[3][r] * attv[3];
        #pragma unroll
        for (int off = 1; off < 16; off <<= 1) {
            h0v += __shfl_xor(h0v, off);
            h1v += __shfl_xor(h1v, off);
        }
        if (col == 0) {
            int gm = m0 + w * 16 + quad * 4 + r;
            if (gm < M) {
                e_out[gm * NH + hbase] = h0v;
                e_out[gm * NH + hbase + 1] = h1v;
            }
        }
    }
}

// ---------------- per-edge exp(leaky(es+ed)) and segment denominator ----------------
__global__ void edge_exp_sum(const float* __restrict__ es, const float* __restrict__ ed,
                             const int* __restrict__ src, const int* __restrict__ dst,
                             float* __restrict__ exb, float* __restrict__ segsum) {
    int g = blockIdx.x * blockDim.x + threadIdx.x;
    if (g >= N_EDGES * NH) return;
    int e = g >> 3, h = g & 7;
    int s = src[e], d = dst[e];
    float x = es[s * NH + h] + ed[d * NH + h];
    x = (x >= 0.f) ? x : 0.2f * x;
    float ex = expf(x);
    exb[g] = ex;
    atomicAdd(&segsum[d * NH + h], ex);
}

// ---------------- message scatter: out[dst] += hs[src] * alpha ----------------
__global__ __launch_bounds__(256) void msg_scatter(const float* __restrict__ exb,
                                                   const float* __restrict__ segsum,
                                                   const int* __restrict__ src,
                                                   const int* __restrict__ dst,
                                                   const float* __restrict__ hs,
                                                   float* __restrict__ out,
                                                   float* __restrict__ alpha_out) {
    int e = blockIdx.x;
    int tid = threadIdx.x;
    int s = src[e], d = dst[e];
    int h = tid >> 5;
    float alpha = exb[e * NH + h] / (segsum[d * NH + h] + 1e-16f);
    float v = hs[(size_t)s * HC + tid] * alpha;
    atomicAdd(&out[(size_t)d * HC + tid], v);
    if (alpha_out != nullptr && tid < NH) {
        alpha_out[e * NH + tid] = exb[e * NH + tid] / (segsum[d * NH + tid] + 1e-16f);
    }
}

// ---------------- layernorm (+bias in) + relu, in place, row = 256 ----------------
__global__ __launch_bounds__(256) void ln_relu(float* __restrict__ x, const float* __restrict__ bias,
                                               const float* __restrict__ g, const float* __restrict__ b) {
    int n = blockIdx.x;
    int tid = threadIdx.x;
    float v = x[(size_t)n * HC + tid] + bias[tid];
    float s1 = v, s2 = v * v;
    #pragma unroll
    for (int off = 32; off; off >>= 1) {
        s1 += __shfl_down(s1, off);
        s2 += __shfl_down(s2, off);
    }
    __shared__ float w1[4], w2[4];
    __shared__ float mu_s, rstd_s;
    int wid = tid >> 6, lane = tid & 63;
    if (lane == 0) { w1[wid] = s1; w2[wid] = s2; }
    __syncthreads();
    if (tid == 0) {
        float t1 = w1[0] + w1[1] + w1[2] + w1[3];
        float t2 = w2[0] + w2[1] + w2[2] + w2[3];
        float mu = t1 * (1.f / 256.f);
        float var = t2 * (1.f / 256.f) - mu * mu;
        mu_s = mu;
        rstd_s = rsqrtf(var + 1e-5f);
    }
    __syncthreads();
    float y = (v - mu_s) * rstd_s * g[tid] + b[tid];
    x[(size_t)n * HC + tid] = (y > 0.f) ? y : 0.f;
}

// ---------------- column-sum accumulate (mean pooling), 256 cols ----------------
__global__ __launch_bounds__(256) void pool_accum(const float* __restrict__ x, float* __restrict__ sums) {
    int tid = threadIdx.x;
    float acc = 0.f;
    for (int r = blockIdx.x; r < N_NODES; r += gridDim.x)
        acc += x[(size_t)r * HC + tid];
    atomicAdd(&sums[tid], acc);
}

// ---------------- x_pkg column-sum (128 cols), 2 rows per block-iter ----------------
__global__ __launch_bounds__(256) void pkg_accum(const float* __restrict__ x, float* __restrict__ sums) {
    int tid = threadIdx.x;
    int col = tid & 127;
    int rof = tid >> 7;
    float acc = 0.f;
    for (int r = blockIdx.x * 2 + rof; r < N_NODES; r += gridDim.x * 2)
        acc += x[(size_t)r * D_IN + col];
    atomicAdd(&sums[col], acc);
}

// ---------------- final classifier dot ----------------
__global__ __launch_bounds__(256) void logits_k(const float* __restrict__ psums,
                                                const float* __restrict__ ksums,
                                                const float* __restrict__ Wc,
                                                const float* __restrict__ bc,
                                                float* __restrict__ out) {
    int tid = threadIdx.x;
    const float inv = 1.f / (float)N_NODES;
    float acc = 0.f;
    for (int i = tid; i < N_TYPES * HC; i += 256) acc += psums[i] * inv * Wc[i];
    if (tid < D_IN) acc += ksums[tid] * inv * Wc[N_TYPES * HC + tid];
    #pragma unroll
    for (int off = 32; off; off >>= 1) acc += __shfl_down(acc, off);
    __shared__ float w[4];
    if ((tid & 63) == 0) w[tid >> 6] = acc;
    __syncthreads();
    if (tid == 0) out[0] = w[0] + w[1] + w[2] + w[3] + bc[0];
}

static inline void zf(float* p, int n, hipStream_t stream) {
    int n4 = n >> 2;
    zero4<<<(n4 + 255) / 256, 256, 0, stream>>>((float4*)p, n4);
}

extern "C" void kernel_launch(void* const* d_in, const int* in_sizes, int n_in,
                              void* d_out, int out_size, void* d_ws, size_t ws_size,
                              hipStream_t stream) {
    const float* x_pkg    = (const float*)d_in[0];
    const float* x_tgt    = (const float*)d_in[1];
    const int*   ei       = (const int*)d_in[2];
    const float* W1_src   = (const float*)d_in[3];
    const float* W1_dst   = (const float*)d_in[4];
    const float* att1_src = (const float*)d_in[5];
    const float* att1_dst = (const float*)d_in[6];
    const float* b1       = (const float*)d_in[7];
    const float* W2_src   = (const float*)d_in[8];
    const float* W2_dst   = (const float*)d_in[9];
    const float* att2_src = (const float*)d_in[10];
    const float* att2_dst = (const float*)d_in[11];
    const float* b2       = (const float*)d_in[12];
    const float* gamma    = (const float*)d_in[13];
    const float* beta     = (const float*)d_in[14];
    const float* Wc       = (const float*)d_in[15];
    const float* bc       = (const float*)d_in[16];
    float* out = (float*)d_out;

    float* ws = (float*)d_ws;
    const size_t BIG = (size_t)N_NODES * HC;          // 7,680,000
    float* bufA   = ws;
    float* bufB   = bufA + BIG;
    float* es     = bufB + BIG;                        // 240,000
    float* ed     = es + (size_t)N_NODES * NH;
    float* segsum = ed + (size_t)N_NODES * NH;
    float* exb    = segsum + (size_t)N_NODES * NH;     // 800,000
    float* psums  = exb + (size_t)N_EDGES * NH;        // 1536
    float* ksums  = psums + N_TYPES * HC;              // 128

    dim3 ggrid((N_NODES + 63) / 64, HC / 64);
    const int NN8 = N_NODES * NH;
    const int E8 = N_EDGES * NH;

    zf(psums, N_TYPES * HC, stream);
    zf(ksums, D_IN, stream);
    pkg_accum<<<256, 256, 0, stream>>>(x_pkg, ksums);

    for (int t = 0; t < N_TYPES; ++t) {
        const int* src_t = ei + (size_t)t * 2 * N_EDGES;
        const int* dst_t = src_t + N_EDGES;

        // ---- layer 1 ----
        // hd1: only need ed
        gemm_att<<<ggrid, 256, 0, stream>>>(x_tgt + (size_t)t * N_NODES * D_IN,
                                            W1_dst + (size_t)t * D_IN * HC, nullptr,
                                            att1_dst + t * HC, ed, N_NODES, D_IN, HC);
        // hs1 -> bufA, es
        gemm_att<<<ggrid, 256, 0, stream>>>(x_pkg, W1_src + (size_t)t * D_IN * HC, bufA,
                                            att1_src + t * HC, es, N_NODES, D_IN, HC);
        zf(segsum, NN8, stream);
        edge_exp_sum<<<(E8 + 255) / 256, 256, 0, stream>>>(es, ed, src_t, dst_t, exb, segsum);
        zf(bufB, (int)BIG, stream);
        msg_scatter<<<N_EDGES, 256, 0, stream>>>(exb, segsum, src_t, dst_t, bufA, bufB, nullptr);
        ln_relu<<<N_NODES, 256, 0, stream>>>(bufB, b1 + t * HC, gamma + t * HC, beta + t * HC);

        // ---- layer 2 ----
        // hd2 = x1 @ W2_dst: only need ed
        gemm_att<<<ggrid, 256, 0, stream>>>(bufB, W2_dst + (size_t)t * HC * HC, nullptr,
                                            att2_dst + t * HC, ed, N_NODES, HC, HC);
        // hs2 -> bufA, es
        gemm_att<<<ggrid, 256, 0, stream>>>(x_pkg, W2_src + (size_t)t * D_IN * HC, bufA,
                                            att2_src + t * HC, es, N_NODES, D_IN, HC);
        zf(segsum, NN8, stream);
        edge_exp_sum<<<(E8 + 255) / 256, 256, 0, stream>>>(es, ed, src_t, dst_t, exb, segsum);
        zf(bufB, (int)BIG, stream);
        msg_scatter<<<N_EDGES, 256, 0, stream>>>(exb, segsum, src_t, dst_t, bufA, bufB,
                                                 out + 1 + (size_t)t * N_EDGES * NH);
        ln_relu<<<N_NODES, 256, 0, stream>>>(bufB, b2 + t * HC, gamma + t * HC, beta + t * HC);
        pool_accum<<<512, 256, 0, stream>>>(bufB, psums + t * HC);
    }

    logits_k<<<1, 256, 0, stream>>>(psums, ksums, Wc, bc, out);
}

// Round 3
// 1480.499 us; speedup vs baseline: 2.3946x; 1.5273x over previous
//
#include <hip/hip_runtime.h>
#include <hip/hip_bf16.h>
#include <cstddef>

#define N_NODES 30000
#define N_EDGES 100000
#define N_TYPES 6
#define D_IN 128
#define HC 256
#define NH 8
#define CH 32

typedef __attribute__((ext_vector_type(8))) unsigned short ushort8_t;
typedef __attribute__((ext_vector_type(8))) __bf16 bf16x8;
typedef __attribute__((ext_vector_type(4))) float floatx4;

__device__ inline unsigned short f2bf(float f) {
    unsigned u = __float_as_uint(f);
    u += 0x7fffu + ((u >> 16) & 1u);
    return (unsigned short)(u >> 16);
}

// ---------------- small fills ----------------
__global__ void zero4(float4* __restrict__ p, int n4) {
    int g = blockIdx.x * blockDim.x + threadIdx.x;
    if (g < n4) p[g] = make_float4(0.f, 0.f, 0.f, 0.f);
}
__global__ void zero_i(int* __restrict__ p, int n) {
    int g = blockIdx.x * blockDim.x + threadIdx.x;
    if (g < n) p[g] = 0;
}

// ---------------- CSR build ----------------
__global__ void hist_k(const int* __restrict__ dst, int* __restrict__ counts) {
    int e = blockIdx.x * blockDim.x + threadIdx.x;
    if (e < N_EDGES) atomicAdd(&counts[dst[e]], 1);
}

#define SCAN_T 1024
#define SCAN_C 30
__global__ __launch_bounds__(1024) void scan_k(const int* __restrict__ counts,
                                               int* __restrict__ row_ptr,
                                               int* __restrict__ cursor) {
    __shared__ int part[SCAN_T];
    int tid = threadIdx.x;
    int base = tid * SCAN_C;
    int loc[SCAN_C];
    int s = 0;
    #pragma unroll
    for (int i = 0; i < SCAN_C; ++i) {
        int idx = base + i;
        int v = (idx < N_NODES) ? counts[idx] : 0;
        loc[i] = s; s += v;
    }
    part[tid] = s;
    __syncthreads();
    int tot = s;
    for (int d = 1; d < SCAN_T; d <<= 1) {
        int v = (tid >= d) ? part[tid - d] : 0;
        __syncthreads();
        part[tid] += v;
        __syncthreads();
    }
    int off = part[tid] - tot;
    #pragma unroll
    for (int i = 0; i < SCAN_C; ++i) {
        int idx = base + i;
        if (idx < N_NODES) { int r = off + loc[i]; row_ptr[idx] = r; cursor[idx] = r; }
    }
    if (tid == SCAN_T - 1) row_ptr[N_NODES] = part[SCAN_T - 1];
}

__global__ void fill_k(const int* __restrict__ src, const int* __restrict__ dst,
                       int* __restrict__ cursor, int2* __restrict__ elist) {
    int e = blockIdx.x * blockDim.x + threadIdx.x;
    if (e < N_EDGES) {
        int pos = atomicAdd(&cursor[dst[e]], 1);
        elist[pos] = make_int2(src[e], e);
    }
}

// ---------------- attention weight precompute: w[k,h] = sum_c W[k,h*32+c]*a[h,c] ----------------
// covers all 6 types, both layers: wd1 [6][128][8], wd2 [6][256][8]
__global__ void att_weight_all(const float* __restrict__ W1d, const float* __restrict__ a1d,
                               const float* __restrict__ W2d, const float* __restrict__ a2d,
                               float* __restrict__ wd1, float* __restrict__ wd2) {
    int g = blockIdx.x * blockDim.x + threadIdx.x;
    const int per_t = (D_IN + HC) * NH;          // 3072
    if (g >= N_TYPES * per_t) return;
    int t = g / per_t, r = g % per_t;
    if (r < D_IN * NH) {
        int k = r >> 3, h = r & 7;
        const float* wr = W1d + (size_t)t * D_IN * HC + (size_t)k * HC + h * CH;
        const float* ar = a1d + t * HC + h * CH;
        float s = 0.f;
        #pragma unroll
        for (int c = 0; c < CH; ++c) s += wr[c] * ar[c];
        wd1[t * D_IN * NH + r] = s;
    } else {
        r -= D_IN * NH;
        int k = r >> 3, h = r & 7;
        const float* wr = W2d + (size_t)t * HC * HC + (size_t)k * HC + h * CH;
        const float* ar = a2d + t * HC + h * CH;
        float s = 0.f;
        #pragma unroll
        for (int c = 0; c < CH; ++c) s += wr[c] * ar[c];
        wd2[t * HC * NH + r] = s;
    }
}

// ---------------- MFMA bf16 GEMM with fused attention-logit epilogue ----------------
__global__ __launch_bounds__(256) void gemm_att(const float* __restrict__ A,
                                                const float* __restrict__ B,
                                                float* __restrict__ Cp,
                                                const float* __restrict__ att,
                                                float* __restrict__ e_out,
                                                int M, int K, int N) {
    __shared__ unsigned short As[64 * 40];
    __shared__ unsigned short Bs[64 * 40];

    const int tid = threadIdx.x;
    const int w = tid >> 6;
    const int lane = tid & 63;
    const int col = lane & 15;
    const int quad = lane >> 4;
    const int m0 = blockIdx.x * 64;
    const int n0 = blockIdx.y * 64;

    const int am = tid >> 2;
    const int ak = (tid & 3) * 8;
    const int bk2 = (tid >> 4) * 2;
    const int bn4 = (tid & 15) * 4;

    floatx4 acc[4];
    #pragma unroll
    for (int ct = 0; ct < 4; ++ct) acc[ct] = (floatx4){0.f, 0.f, 0.f, 0.f};

    for (int k0 = 0; k0 < K; k0 += 32) {
        {
            int gm = m0 + am;
            float4 f0 = make_float4(0, 0, 0, 0), f1 = make_float4(0, 0, 0, 0);
            if (gm < M) {
                const float* ap = A + (size_t)gm * K + k0 + ak;
                f0 = *(const float4*)ap;
                f1 = *(const float4*)(ap + 4);
            }
            ushort8_t v;
            v[0] = f2bf(f0.x); v[1] = f2bf(f0.y); v[2] = f2bf(f0.z); v[3] = f2bf(f0.w);
            v[4] = f2bf(f1.x); v[5] = f2bf(f1.y); v[6] = f2bf(f1.z); v[7] = f2bf(f1.w);
            *(ushort8_t*)&As[am * 40 + ak] = v;
        }
        {
            const float4 r0 = *(const float4*)&B[(size_t)(k0 + bk2) * N + n0 + bn4];
            const float4 r1 = *(const float4*)&B[(size_t)(k0 + bk2 + 1) * N + n0 + bn4];
            float a0[4] = {r0.x, r0.y, r0.z, r0.w};
            float a1[4] = {r1.x, r1.y, r1.z, r1.w};
            #pragma unroll
            for (int j = 0; j < 4; ++j) {
                unsigned pk = (unsigned)f2bf(a0[j]) | ((unsigned)f2bf(a1[j]) << 16);
                *(unsigned*)&Bs[(bn4 + j) * 40 + bk2] = pk;
            }
        }
        __syncthreads();
        {
            ushort8_t araw = *(const ushort8_t*)&As[(w * 16 + col) * 40 + quad * 8];
            bf16x8 af = __builtin_bit_cast(bf16x8, araw);
            #pragma unroll
            for (int ct = 0; ct < 4; ++ct) {
                ushort8_t braw = *(const ushort8_t*)&Bs[(ct * 16 + col) * 40 + quad * 8];
                bf16x8 bf = __builtin_bit_cast(bf16x8, braw);
                acc[ct] = __builtin_amdgcn_mfma_f32_16x16x32_bf16(af, bf, acc[ct], 0, 0, 0);
            }
        }
        __syncthreads();
    }

    if (Cp != nullptr) {
        #pragma unroll
        for (int ct = 0; ct < 4; ++ct) {
            #pragma unroll
            for (int r = 0; r < 4; ++r) {
                int gm = m0 + w * 16 + quad * 4 + r;
                if (gm < M) Cp[(size_t)gm * N + n0 + ct * 16 + col] = acc[ct][r];
            }
        }
    }

    float attv[4];
    #pragma unroll
    for (int ct = 0; ct < 4; ++ct) attv[ct] = att[n0 + ct * 16 + col];
    const int hbase = n0 >> 5;
    #pragma unroll
    for (int r = 0; r < 4; ++r) {
        float h0v = acc[0][r] * attv[0] + acc[1][r] * attv[1];
        float h1v = acc[2][r] * attv[2] + acc[3][r] * attv[3];
        #pragma unroll
        for (int off = 1; off < 16; off <<= 1) {
            h0v += __shfl_xor(h0v, off);
            h1v += __shfl_xor(h1v, off);
        }
        if (col == 0) {
            int gm = m0 + w * 16 + quad * 4 + r;
            if (gm < M) {
                e_out[gm * NH + hbase] = h0v;
                e_out[gm * NH + hbase + 1] = h1v;
            }
        }
    }
}

// ---------------- fused CSR gather + softmax + bias + LN + ReLU ----------------
// one wave per dst node; lane covers channels [lane*4, lane*4+4), head = lane>>3
__global__ __launch_bounds__(256) void gather_ln(const int* __restrict__ row_ptr,
                                                 const int2* __restrict__ elist,
                                                 const float* __restrict__ es,
                                                 const float* __restrict__ xd, int Kd,
                                                 const float* __restrict__ w_att,
                                                 const float* __restrict__ hs,
                                                 const float* __restrict__ bias,
                                                 const float* __restrict__ gam,
                                                 const float* __restrict__ bet,
                                                 float* __restrict__ xout,
                                                 float* __restrict__ alpha_out) {
    const int lane = threadIdx.x & 63;
    const int d = blockIdx.x * 4 + (threadIdx.x >> 6);
    if (d >= N_NODES) return;

    // ---- ed[d, 0..7] = x_dst[d,:] @ w_att ----
    float edv[8];
    #pragma unroll
    for (int h = 0; h < 8; ++h) edv[h] = 0.f;
    for (int k = lane; k < Kd; k += 64) {
        float xv = xd[(size_t)d * Kd + k];
        const float* wr = w_att + k * 8;
        #pragma unroll
        for (int h = 0; h < 8; ++h) edv[h] += xv * wr[h];
    }
    #pragma unroll
    for (int off = 1; off < 64; off <<= 1) {
        #pragma unroll
        for (int h = 0; h < 8; ++h) edv[h] += __shfl_xor(edv[h], off);
    }

    const int h_l = lane >> 3;
    const float ed_mine = edv[h_l];
    const int e0 = row_ptr[d], e1 = row_ptr[d + 1];

    // ---- denominator (redundant across the 8 lanes of a head; cheap) ----
    float den = 0.f;
    for (int i = e0; i < e1; ++i) {
        int s = elist[i].x;
        float x = es[s * NH + h_l] + ed_mine;
        x = (x >= 0.f) ? x : 0.2f * x;
        den += __expf(x);
    }
    float den_h = __shfl(den, (lane & 7) * 8);   // den of head (lane&7)
    float inv_den = 1.f / (den + 1e-16f);

    // ---- message accumulation ----
    float4 acc = make_float4(0.f, 0.f, 0.f, 0.f);
    for (int i = e0; i < e1; ++i) {
        int s = elist[i].x;
        float x = es[s * NH + h_l] + ed_mine;
        x = (x >= 0.f) ? x : 0.2f * x;
        float al = __expf(x) * inv_den;
        float4 hv = *(const float4*)&hs[(size_t)s * HC + lane * 4];
        acc.x += al * hv.x; acc.y += al * hv.y; acc.z += al * hv.z; acc.w += al * hv.w;
    }

    // ---- alpha output (layer 2 only): lane l<8 writes head l of each edge ----
    if (alpha_out != nullptr && lane < 8) {
        float inv_h = 1.f / (den_h + 1e-16f);
        float ed_h = edv[lane];
        for (int i = e0; i < e1; ++i) {
            int s = elist[i].x, eid = elist[i].y;
            float x = es[s * NH + lane] + ed_h;
            x = (x >= 0.f) ? x : 0.2f * x;
            alpha_out[(size_t)eid * NH + lane] = __expf(x) * inv_h;
        }
    }

    // ---- bias + LN + ReLU ----
    float4 bv = *(const float4*)&bias[lane * 4];
    acc.x += bv.x; acc.y += bv.y; acc.z += bv.z; acc.w += bv.w;
    float s1 = acc.x + acc.y + acc.z + acc.w;
    float s2 = acc.x * acc.x + acc.y * acc.y + acc.z * acc.z + acc.w * acc.w;
    #pragma unroll
    for (int off = 1; off < 64; off <<= 1) {
        s1 += __shfl_xor(s1, off);
        s2 += __shfl_xor(s2, off);
    }
    float mu = s1 * (1.f / 256.f);
    float var = s2 * (1.f / 256.f) - mu * mu;
    float rstd = rsqrtf(var + 1e-5f);
    float4 g4 = *(const float4*)&gam[lane * 4];
    float4 b4 = *(const float4*)&bet[lane * 4];
    float4 y;
    y.x = (acc.x - mu) * rstd * g4.x + b4.x;
    y.y = (acc.y - mu) * rstd * g4.y + b4.y;
    y.z = (acc.z - mu) * rstd * g4.z + b4.z;
    y.w = (acc.w - mu) * rstd * g4.w + b4.w;
    y.x = fmaxf(y.x, 0.f); y.y = fmaxf(y.y, 0.f); y.z = fmaxf(y.z, 0.f); y.w = fmaxf(y.w, 0.f);
    *(float4*)&xout[(size_t)d * HC + lane * 4] = y;
}

// ---------------- column sums for pooling ----------------
__global__ __launch_bounds__(256) void pool_accum(const float* __restrict__ x, float* __restrict__ sums) {
    int tid = threadIdx.x;
    float acc = 0.f;
    for (int r = blockIdx.x; r < N_NODES; r += gridDim.x)
        acc += x[(size_t)r * HC + tid];
    atomicAdd(&sums[tid], acc);
}
__global__ __launch_bounds__(256) void pkg_accum(const float* __restrict__ x, float* __restrict__ sums) {
    int tid = threadIdx.x;
    int col = tid & 127;
    int rof = tid >> 7;
    float acc = 0.f;
    for (int r = blockIdx.x * 2 + rof; r < N_NODES; r += gridDim.x * 2)
        acc += x[(size_t)r * D_IN + col];
    atomicAdd(&sums[col], acc);
}

// ---------------- final classifier dot ----------------
__global__ __launch_bounds__(256) void logits_k(const float* __restrict__ psums,
                                                const float* __restrict__ ksums,
                                                const float* __restrict__ Wc,
                                                const float* __restrict__ bc,
                                                float* __restrict__ out) {
    int tid = threadIdx.x;
    const float inv = 1.f / (float)N_NODES;
    float acc = 0.f;
    for (int i = tid; i < N_TYPES * HC; i += 256) acc += psums[i] * inv * Wc[i];
    if (tid < D_IN) acc += ksums[tid] * inv * Wc[N_TYPES * HC + tid];
    #pragma unroll
    for (int off = 32; off; off >>= 1) acc += __shfl_down(acc, off);
    __shared__ float w[4];
    if ((tid & 63) == 0) w[tid >> 6] = acc;
    __syncthreads();
    if (tid == 0) out[0] = w[0] + w[1] + w[2] + w[3] + bc[0];
}

static inline void zf(float* p, int n, hipStream_t stream) {
    int n4 = (n + 3) >> 2;
    zero4<<<(n4 + 255) / 256, 256, 0, stream>>>((float4*)p, n4);
}

extern "C" void kernel_launch(void* const* d_in, const int* in_sizes, int n_in,
                              void* d_out, int out_size, void* d_ws, size_t ws_size,
                              hipStream_t stream) {
    const float* x_pkg    = (const float*)d_in[0];
    const float* x_tgt    = (const float*)d_in[1];
    const int*   ei       = (const int*)d_in[2];
    const float* W1_src   = (const float*)d_in[3];
    const float* W1_dst   = (const float*)d_in[4];
    const float* att1_src = (const float*)d_in[5];
    const float* att1_dst = (const float*)d_in[6];
    const float* b1       = (const float*)d_in[7];
    const float* W2_src   = (const float*)d_in[8];
    const float* W2_dst   = (const float*)d_in[9];
    const float* att2_src = (const float*)d_in[10];
    const float* att2_dst = (const float*)d_in[11];
    const float* b2       = (const float*)d_in[12];
    const float* gamma    = (const float*)d_in[13];
    const float* beta     = (const float*)d_in[14];
    const float* Wc       = (const float*)d_in[15];
    const float* bc       = (const float*)d_in[16];
    float* out = (float*)d_out;

    float* ws = (float*)d_ws;
    const size_t BIG = (size_t)N_NODES * HC;
    float* bufA  = ws;
    float* bufB  = bufA + BIG;
    float* es    = bufB + BIG;                       // 240,000
    float* psums = es + (size_t)N_NODES * NH;        // 1536
    float* ksums = psums + N_TYPES * HC;             // 128
    float* wd1   = ksums + D_IN;                     // 6*128*8
    float* wd2   = wd1 + N_TYPES * D_IN * NH;        // 6*256*8
    int*  counts  = (int*)(wd2 + N_TYPES * HC * NH);
    int*  row_ptr = counts + N_NODES;                // N_NODES+1
    int*  cursor  = row_ptr + N_NODES + 1;
    int2* elist   = (int2*)(cursor + N_NODES);       // N_EDGES int2

    dim3 ggrid((N_NODES + 63) / 64, HC / 64);
    const int gth_blocks = (N_NODES + 3) / 4;

    zf(psums, N_TYPES * HC, stream);
    zf(ksums, D_IN, stream);
    pkg_accum<<<256, 256, 0, stream>>>(x_pkg, ksums);
    {
        int tot = N_TYPES * (D_IN + HC) * NH;
        att_weight_all<<<(tot + 255) / 256, 256, 0, stream>>>(W1_dst, att1_dst, W2_dst, att2_dst, wd1, wd2);
    }

    for (int t = 0; t < N_TYPES; ++t) {
        const int* src_t = ei + (size_t)t * 2 * N_EDGES;
        const int* dst_t = src_t + N_EDGES;

        // ---- CSR build (shared by both layers) ----
        zero_i<<<(N_NODES + 255) / 256, 256, 0, stream>>>(counts, N_NODES);
        hist_k<<<(N_EDGES + 255) / 256, 256, 0, stream>>>(dst_t, counts);
        scan_k<<<1, SCAN_T, 0, stream>>>(counts, row_ptr, cursor);
        fill_k<<<(N_EDGES + 255) / 256, 256, 0, stream>>>(src_t, dst_t, cursor, elist);

        // ---- layer 1 ----
        gemm_att<<<ggrid, 256, 0, stream>>>(x_pkg, W1_src + (size_t)t * D_IN * HC, bufA,
                                            att1_src + t * HC, es, N_NODES, D_IN, HC);
        gather_ln<<<gth_blocks, 256, 0, stream>>>(row_ptr, elist, es,
                                                  x_tgt + (size_t)t * N_NODES * D_IN, D_IN,
                                                  wd1 + t * D_IN * NH, bufA,
                                                  b1 + t * HC, gamma + t * HC, beta + t * HC,
                                                  bufB, nullptr);

        // ---- layer 2 ----
        gemm_att<<<ggrid, 256, 0, stream>>>(x_pkg, W2_src + (size_t)t * D_IN * HC, bufA,
                                            att2_src + t * HC, es, N_NODES, D_IN, HC);
        gather_ln<<<gth_blocks, 256, 0, stream>>>(row_ptr, elist, es,
                                                  bufB, HC,
                                                  wd2 + t * HC * NH, bufA,
                                                  b2 + t * HC, gamma + t * HC, beta + t * HC,
                                                  bufB, out + 1 + (size_t)t * N_EDGES * NH);
        pool_accum<<<512, 256, 0, stream>>>(bufB, psums + t * HC);
    }

    logits_k<<<1, 256, 0, stream>>>(psums, ksums, Wc, bc, out);
}